// Round 6
// baseline (355.465 us; speedup 1.0000x reference)
//
#include <hip/hip_runtime.h>
#include <float.h>

#define BB 16
#define NN 4096
#define CC 64
#define KNN 32
#define NSLICE 16   // select slices per query
#define SSZ 256     // NN / NSLICE
#define CKEEP 8     // kept per slice
#define NQ 65536

// ===========================================================================
// KNN via packed-key select (R13) + 2-src sort network (R15) + wide scalar
// point fetch (R16). Reference arithmetic VARIANT V2:
//   dot = fma(z,z', fma(y,y', x*x'));  xx = ((x*x + y*y) + z*z)  [rn, no fma]
//   pd  = fma(2, dot, -qxx) - xx_c    [== ((dot+dot)-qxx)-xx_c bitwise]
//   key = (~bits(min(pd,0)) & 0xFFFFF000) | (4095 - idx)
//
// R15 post-mortem: three select variants (med3+LDS 108us, med3+s_load 112us,
// 2-src network+LDS 114us) all stick at ~63-67 cyc/pt despite different
// chain structures and load pipes. Shared constant: ONE 16B uniform fetch
// per point per wave (ds_read_b128 / s_load_dwordx4, ~10-12 cyc/instr on
// the shared per-CU pipe; ~21 resident waves all demanding it). R16 tests
// the fetch-issue theory directly: f32x16 AS4 loads -> s_load_dwordx16 =
// 4 points per fetch instr (4x fewer fetch issues). Keys/network/val_buf
// bit-identical to R15; merge certificates ((a) strict 20-bit separation
// at rank 32/33, (b) slice exhaustion) and exact wave-per-query radix
// fallback unchanged. Correct at any flag rate.
// ===========================================================================

typedef __attribute__((ext_vector_type(16))) float f32x16;
#define AS4 __attribute__((address_space(4)))

__device__ __forceinline__ int lane_rank(unsigned long long m) {
    return __builtin_amdgcn_mbcnt_hi((unsigned)(m >> 32),
           __builtin_amdgcn_mbcnt_lo((unsigned)m, 0u));
}

__device__ __forceinline__ unsigned umaxu(unsigned a, unsigned b) {
    return a > b ? a : b;   // v_max_u32
}
__device__ __forceinline__ unsigned uminu(unsigned a, unsigned b) {
    return a < b ? a : b;   // v_min_u32
}
// compare-exchange, descending: a gets max, b gets min (2 two-src ops)
#define CE(a, b) { unsigned _mx = umaxu(a, b); b = uminu(a, b); a = _mx; }

// --------------------------------------------------------------------------
// P: prep. pts4[b*4096+i] = (x,y,z,xx), V2 rn formula; resets flag_cnt.
// --------------------------------------------------------------------------
__global__ __launch_bounds__(256) void prep_kernel(
        const float* __restrict__ xyz, float4* __restrict__ pts4,
        int* __restrict__ flag_cnt) {
#pragma clang fp contract(off)
    const int p = blockIdx.x * 256 + threadIdx.x;
    if (p == 0) flag_cnt[0] = 0;
    const int b = p >> 12;
    const int i = p & (NN - 1);
    const float* xb = xyz + (size_t)b * (3 * NN);
    float x = xb[i], y = xb[NN + i], z = xb[2 * NN + i];
    float xx = ((x * x) + (y * y)) + (z * z);  // rn (contract off)
    pts4[p] = make_float4(x, y, z, xx);
}

// --------------------------------------------------------------------------
// A: select. grid 4096 = (b<<8)|(g<<4)|s, 256 thr = 256 queries. No LDS.
// Points fetched 4-at-a-time via s_load_dwordx16 (uniform AS4); per-slice
// top-8 via the 8-point batched 2-src network (bit-identical to R15).
// --------------------------------------------------------------------------
__global__ __launch_bounds__(256) void knn_select_kernel(
        const float4* __restrict__ pts4, unsigned* __restrict__ val_buf) {
#pragma clang fp contract(off)
    const int tid = threadIdx.x;
    const int blk = blockIdx.x;
    const int s = blk & 15;
    const int g = (blk >> 4) & 15;
    const int b = blk >> 8;
    const float4* pb = pts4 + (b << 12);
    const AS4 f32x16* sp =
        (const AS4 f32x16*)(unsigned long long)(pb + (s << 8));

    const int q = (g << 8) | tid;
    const float4 qp = pb[q];
    const float qx = qp.x, qy = qp.y, qz = qp.z;
    const float nqxx = -qp.w;

    unsigned h0=0,h1=0,h2=0,h3=0,h4=0,h5=0,h6=0,h7=0;
    const unsigned ibase = 4095u - (unsigned)(s << 8);  // idxterm = ibase - j

// key from vector cv, element base e (point = cv[e..e+3]), absolute j = jj
#define KYV(cv, e, jj, dst) { \
    float dot = __builtin_fmaf(qz, cv[(e)+2], \
                __builtin_fmaf(qy, cv[(e)+1], qx * cv[(e)+0])); \
    float pd = __builtin_fmaf(2.0f, dot, nqxx) - cv[(e)+3]; \
    pd = fminf(pd, 0.0f); \
    dst = (~__float_as_uint(pd) & 0xFFFFF000u) \
          | (ibase - (unsigned)(jj)); }

// sort8 desc (Batcher OEMS 19 CE) + half-clean + bitonic-merge8 (12 CE)
#define NET8_AND_MERGE \
    CE(k0,k1) CE(k2,k3) CE(k0,k2) CE(k1,k3) CE(k1,k2) \
    CE(k4,k5) CE(k6,k7) CE(k4,k6) CE(k5,k7) CE(k5,k6) \
    CE(k0,k4) CE(k1,k5) CE(k2,k6) CE(k3,k7) \
    CE(k2,k4) CE(k3,k5) \
    CE(k1,k2) CE(k3,k4) CE(k5,k6) \
    h0 = umaxu(h0, k7); h1 = umaxu(h1, k6); \
    h2 = umaxu(h2, k5); h3 = umaxu(h3, k4); \
    h4 = umaxu(h4, k3); h5 = umaxu(h5, k2); \
    h6 = umaxu(h6, k1); h7 = umaxu(h7, k0); \
    CE(h0,h4) CE(h1,h5) CE(h2,h6) CE(h3,h7) \
    CE(h0,h2) CE(h1,h3) CE(h4,h6) CE(h5,h7) \
    CE(h0,h1) CE(h2,h3) CE(h4,h5) CE(h6,h7)

    for (int j0 = 0; j0 < SSZ; j0 += 16) {
        const int vi = j0 >> 2;
        f32x16 c0 = sp[vi + 0];   // points j0+0 .. j0+3
        f32x16 c1 = sp[vi + 1];   // points j0+4 .. j0+7
        f32x16 c2 = sp[vi + 2];   // points j0+8 .. j0+11
        f32x16 c3 = sp[vi + 3];   // points j0+12 .. j0+15
        {
            unsigned k0,k1,k2,k3,k4,k5,k6,k7;
            KYV(c0, 0, j0+0, k0) KYV(c0, 4, j0+1, k1)
            KYV(c0, 8, j0+2, k2) KYV(c0,12, j0+3, k3)
            KYV(c1, 0, j0+4, k4) KYV(c1, 4, j0+5, k5)
            KYV(c1, 8, j0+6, k6) KYV(c1,12, j0+7, k7)
            NET8_AND_MERGE
        }
        {
            unsigned k0,k1,k2,k3,k4,k5,k6,k7;
            KYV(c2, 0, j0+8,  k0) KYV(c2, 4, j0+9,  k1)
            KYV(c2, 8, j0+10, k2) KYV(c2,12, j0+11, k3)
            KYV(c3, 0, j0+12, k4) KYV(c3, 4, j0+13, k5)
            KYV(c3, 8, j0+14, k6) KYV(c3,12, j0+15, k7)
            NET8_AND_MERGE
        }
    }
#undef KYV
#undef NET8_AND_MERGE

    const int qg = (b << 12) | q;
    unsigned* vp = val_buf + (size_t)(s * CKEEP) * NQ + qg;  // desc t=0..7
#define ST(t, ht) vp[(size_t)(t) * NQ] = ht;
    ST(0,h0) ST(1,h1) ST(2,h2) ST(3,h3)
    ST(4,h4) ST(5,h5) ST(6,h6) ST(7,h7)
#undef ST
}

// --------------------------------------------------------------------------
// B: merge. 64-thr blocks; stage 16x8=128 keys/query to LDS (stride 129);
// 33-step 16-head merge. First 32 picks -> idx_out directly
// (idx = 4095 - (key & 4095)). Certificates -> flag list.
// --------------------------------------------------------------------------
__global__ __launch_bounds__(64) void knn_merge_kernel(
        const unsigned* __restrict__ val_buf, int* __restrict__ idx_out,
        int* __restrict__ flag_list, int* __restrict__ flag_cnt) {
    __shared__ unsigned lv[64 * 129];  // 33 KB
    const int tid = threadIdx.x;
    const int qg = blockIdx.x * 64 + tid;
    unsigned* my = lv + tid * 129;
    for (int t = 0; t < 128; ++t) my[t] = val_buf[(size_t)t * NQ + qg];

    int p0=0,p1=0,p2=0,p3=0,p4=0,p5=0,p6=0,p7=0,
        p8=0,p9=0,p10=0,p11=0,p12=0,p13=0,p14=0,p15=0;
    unsigned v0 =my[0],  v1 =my[8],  v2 =my[16],  v3 =my[24];
    unsigned v4 =my[32], v5 =my[40], v6 =my[48],  v7 =my[56];
    unsigned v8 =my[64], v9 =my[72], v10=my[80],  v11=my[88];
    unsigned v12=my[96], v13=my[104],v14=my[112], v15=my[120];
    int* outp = idx_out + (size_t)qg * KNN;
    unsigned key32 = 0u, key33 = 0u;
    for (int step = 0; step < 33; ++step) {
        unsigned best = v0; int bp = 0;
        if (v1  > best) { best = v1;  bp = 1; }
        if (v2  > best) { best = v2;  bp = 2; }
        if (v3  > best) { best = v3;  bp = 3; }
        if (v4  > best) { best = v4;  bp = 4; }
        if (v5  > best) { best = v5;  bp = 5; }
        if (v6  > best) { best = v6;  bp = 6; }
        if (v7  > best) { best = v7;  bp = 7; }
        if (v8  > best) { best = v8;  bp = 8; }
        if (v9  > best) { best = v9;  bp = 9; }
        if (v10 > best) { best = v10; bp = 10; }
        if (v11 > best) { best = v11; bp = 11; }
        if (v12 > best) { best = v12; bp = 12; }
        if (v13 > best) { best = v13; bp = 13; }
        if (v14 > best) { best = v14; bp = 14; }
        if (v15 > best) { best = v15; bp = 15; }
        if (step == 32) { key33 = best; break; }
        outp[step] = 4095 - (int)(best & 4095u);
        if (step == 31) key32 = best;
        if      (bp==0)  { ++p0;  v0  = (p0 <8)?my[p0]      :0u; }
        else if (bp==1)  { ++p1;  v1  = (p1 <8)?my[8+p1]    :0u; }
        else if (bp==2)  { ++p2;  v2  = (p2 <8)?my[16+p2]   :0u; }
        else if (bp==3)  { ++p3;  v3  = (p3 <8)?my[24+p3]   :0u; }
        else if (bp==4)  { ++p4;  v4  = (p4 <8)?my[32+p4]   :0u; }
        else if (bp==5)  { ++p5;  v5  = (p5 <8)?my[40+p5]   :0u; }
        else if (bp==6)  { ++p6;  v6  = (p6 <8)?my[48+p6]   :0u; }
        else if (bp==7)  { ++p7;  v7  = (p7 <8)?my[56+p7]   :0u; }
        else if (bp==8)  { ++p8;  v8  = (p8 <8)?my[64+p8]   :0u; }
        else if (bp==9)  { ++p9;  v9  = (p9 <8)?my[72+p9]   :0u; }
        else if (bp==10) { ++p10; v10 = (p10<8)?my[80+p10]  :0u; }
        else if (bp==11) { ++p11; v11 = (p11<8)?my[88+p11]  :0u; }
        else if (bp==12) { ++p12; v12 = (p12<8)?my[96+p12]  :0u; }
        else if (bp==13) { ++p13; v13 = (p13<8)?my[104+p13] :0u; }
        else if (bp==14) { ++p14; v14 = (p14<8)?my[112+p14] :0u; }
        else             { ++p15; v15 = (p15<8)?my[120+p15] :0u; }
    }

    // certificates: (a) strict 20-bit separation at the 32/33 boundary;
    // (b) every slice's 8th kept key < key33 (merge saw the true top-33).
    bool flag = ((key32 >> 12) == (key33 >> 12));
    for (int sl = 0; sl < 16; ++sl)
        flag = flag || (my[sl * 8 + 7] >= key33);
    if (flag) {
        int pos = atomicAdd(flag_cnt, 1);
        flag_list[pos] = qg;
    }
}

// --------------------------------------------------------------------------
// B2: exact fallback, wave-per-query over the compacted flag list.
// Full-precision mono keys in 64 statically-indexed VGPRs; 32-step radix
// select -> exact 32nd key; indices via ballot compaction (index order,
// eq-ties take first `budget` -- exact reference tie semantics).
// --------------------------------------------------------------------------
__global__ __launch_bounds__(256) void knn_fallback_kernel(
        const float* __restrict__ xyz, const int* __restrict__ flag_list,
        const int* __restrict__ flag_cnt, int* __restrict__ idx_out) {
#pragma clang fp contract(off)
    const int nflag = flag_cnt[0];
    const int lane = threadIdx.x & 63;
    const int wid = (blockIdx.x * 256 + threadIdx.x) >> 6;
    const int nw = (gridDim.x * 256) >> 6;
    for (int w = wid; w < nflag; w += nw) {
        const int qg = flag_list[w];
        const int b = qg >> 12;
        const int q = qg & (NN - 1);
        const float* xb = xyz + (size_t)b * (3 * NN);
        const float qx = xb[q], qy = xb[NN + q], qz = xb[2 * NN + q];
        const float qxx = ((qx * qx) + (qy * qy)) + (qz * qz);
        const float nqxx = -qxx;

        unsigned key[64];
#pragma unroll
        for (int i = 0; i < 64; ++i) {
            const int j = (i << 6) | lane;
            float x = xb[j], y = xb[NN + j], z = xb[2 * NN + j];
            float xxc = ((x * x) + (y * y)) + (z * z);
            float dot = __builtin_fmaf(qz, z, __builtin_fmaf(qy, y, qx * x));
            float pd = __builtin_fmaf(2.0f, dot, nqxx) - xxc;
            unsigned u = __float_as_uint(pd);
            key[i] = u ^ (unsigned)(((int)u >> 31) | 0x80000000);
        }

        // largest t with #{key >= t} >= 32  ==  32nd-largest key
        unsigned cur = 0u;
        for (int bit = 31; bit >= 0; --bit) {
            const unsigned cand = cur | (1u << bit);
            int c = 0;
#pragma unroll
            for (int i = 0; i < 64; ++i) c += (key[i] >= cand) ? 1 : 0;
#pragma unroll
            for (int o = 32; o >= 1; o >>= 1) c += __shfl_xor(c, o, 64);
            if (c >= 32) cur = cand;  // uniform after butterfly
        }

        // exact gt/eq totals
        int ge = 0;
#pragma unroll
        for (int i = 0; i < 64; ++i) {
            ge += (key[i] > cur) ? 1 : 0;
            ge += (key[i] == cur) ? 0x10000 : 0;
        }
#pragma unroll
        for (int o = 32; o >= 1; o >>= 1) ge += __shfl_xor(ge, o, 64);
        const int gt_total = ge & 0xFFFF;
        const int budget = min(ge >> 16, 32 - gt_total);

        int* outp = idx_out + (size_t)qg * KNN;
        int slot = 0, neq = 0;
#pragma unroll
        for (int i = 0; i < 64; ++i) {
            const bool isgt = key[i] > cur;
            const bool iseq = key[i] == cur;
            const unsigned long long mgt = __ballot(isgt);
            const unsigned long long meq = __ballot(iseq);
            if (isgt) outp[slot + lane_rank(mgt)] = (i << 6) | lane;
            if (iseq) {
                const int r = neq + lane_rank(meq);
                if (r < budget) outp[gt_total + r] = (i << 6) | lane;
            }
            slot += __builtin_popcountll(mgt);
            neq += __builtin_popcountll(meq);
        }
    }
}

// --------------------------------------------------------------------------
// gather / sigma / finalize: unchanged.
// --------------------------------------------------------------------------
__global__ __launch_bounds__(256) void gather_minmax_kernel(
        const float* __restrict__ feats, const int* __restrict__ idx_in,
        float* __restrict__ mx_buf, float* __restrict__ mn_buf,
        double* __restrict__ partials) {
    const int tid = threadIdx.x;
    const int w = tid >> 6;
    const int lane = tid & 63;
    const int q = blockIdx.x * 4 + w;
    const int b = q >> 12;
    const float* fb = feats + (size_t)b * (NN * CC);
    const float center = feats[(size_t)q * CC + lane];
    const int* ip = idx_in + (size_t)q * KNN;

    float mx = -FLT_MAX, mn = FLT_MAX;
    double ss = 0.0;
#pragma unroll 4
    for (int k = 0; k < KNN; ++k) {
        int nb = ip[k];
        float v = fb[(size_t)nb * CC + lane];
        float off = v - center;
        mx = fmaxf(mx, off);
        mn = fminf(mn, off);
        double od = (double)off;
        ss = fma(od, od, ss);
    }
    mx_buf[(size_t)q * CC + lane] = mx;
    mn_buf[(size_t)q * CC + lane] = mn;

#pragma unroll
    for (int o = 32; o >= 1; o >>= 1) ss += __shfl_down(ss, o, 64);
    __shared__ double wsum[4];
    if (lane == 0) wsum[w] = ss;
    __syncthreads();
    if (tid == 0) partials[blockIdx.x] = (wsum[0] + wsum[1]) + (wsum[2] + wsum[3]);
}

__global__ __launch_bounds__(256) void sigma_kernel(const double* __restrict__ partials,
                                                    float* __restrict__ sigma) {
    __shared__ double red[256];
    double s = 0.0;
    for (int i = threadIdx.x; i < 16384; i += 256) s += partials[i];
    red[threadIdx.x] = s;
    __syncthreads();
    for (int o = 128; o >= 1; o >>= 1) {
        if (threadIdx.x < o) red[threadIdx.x] += red[threadIdx.x + o];
        __syncthreads();
    }
    if (threadIdx.x == 0) sigma[0] = (float)(red[0] * (1.0 / 134217728.0));
}

__global__ __launch_bounds__(256) void finalize_kernel(
        const float* __restrict__ mx_buf, const float* __restrict__ mn_buf,
        const float* __restrict__ alpha, const float* __restrict__ beta,
        const float* __restrict__ sigma, float* __restrict__ out) {
#pragma clang fp contract(off)
    const int e = blockIdx.x * 256 + threadIdx.x;
    const int c = e & (CC - 1);
    const float s = sigma[0] + 1e-5f;
    const float a = alpha[c];
    const float bt = beta[c];
    const float off = (a >= 0.f) ? mx_buf[e] : mn_buf[e];
    const float t = off / s;
    out[e] = (t * a) + bt;
}

extern "C" void kernel_launch(void* const* d_in, const int* in_sizes, int n_in,
                              void* d_out, int out_size, void* d_ws, size_t ws_size,
                              hipStream_t stream) {
    (void)in_sizes; (void)n_in; (void)out_size; (void)ws_size;
    const float* xyz   = (const float*)d_in[0];  // [16,3,4096]
    const float* feats = (const float*)d_in[1];  // [16,4096,64]
    const float* alpha = (const float*)d_in[2];  // [64]
    const float* beta  = (const float*)d_in[3];  // [64]
    float* out = (float*)d_out;                  // [16,4096,64]

    char* ws = (char*)d_ws;
    // Lifetimes:
    //   val_buf   [0, 33,554,432)          select->merge(read); dead after.
    //   mx/mn     alias val region          written by gather (post-merge).
    //   idx_buf   [33,554,432, 41,943,040)  merge/fallback write, gather reads.
    //   flag_list [41,943,040, +256 KB)     merge->fallback.
    //   flag_cnt  42,205,184 (4 B)
    //   pts4      [42,205,248, +1 MB)       prep->select; dead after select.
    //   partials  alias pts4 start          written by gather.
    //   sigma     43,254,784 (after pts4)
    unsigned* val_buf  = (unsigned*)ws;
    float*    mx_buf   = (float*)ws;                  // [0, 16.78M)
    float*    mn_buf   = (float*)(ws + 16777216);     // [16.78M, 33.55M)
    int*      idx_buf  = (int*)(ws + 33554432);
    int*      flag_list= (int*)(ws + 41943040);
    int*      flag_cnt = (int*)(ws + 42205184);
    float4*   pts4     = (float4*)(ws + 42205248);    // 64B-aligned
    double*   partials = (double*)(ws + 42205248);    // alias pts4 (dead)
    float*    sigma    = (float*)(ws + 43254784);

    prep_kernel<<<NQ / 256, 256, 0, stream>>>(xyz, pts4, flag_cnt);
    knn_select_kernel<<<BB * 16 * NSLICE, 256, 0, stream>>>(pts4, val_buf);
    knn_merge_kernel<<<NQ / 64, 64, 0, stream>>>(val_buf, idx_buf,
                                                 flag_list, flag_cnt);
    knn_fallback_kernel<<<256, 256, 0, stream>>>(xyz, flag_list, flag_cnt,
                                                 idx_buf);
    gather_minmax_kernel<<<NQ / 4, 256, 0, stream>>>(feats, idx_buf, mx_buf,
                                                     mn_buf, partials);
    sigma_kernel<<<1, 256, 0, stream>>>(partials, sigma);
    finalize_kernel<<<(NQ * CC) / 256, 256, 0, stream>>>(mx_buf, mn_buf, alpha,
                                                         beta, sigma, out);
}

// Round 7
// 342.536 us; speedup vs baseline: 1.0377x; 1.0377x over previous
//
#include <hip/hip_runtime.h>
#include <float.h>

#define BB 16
#define NN 4096
#define CC 64
#define KNN 32
#define NSLICE 16   // select slices per query
#define SSZ 256     // NN / NSLICE
#define CKEEP 8     // kept per slice
#define NQ 65536

// ===========================================================================
// KNN via packed-key select (R13) + 2-src sort network (R15) + big-block
// occupancy (R17). Reference arithmetic VARIANT V2:
//   dot = fma(z,z', fma(y,y', x*x'));  xx = ((x*x + y*y) + z*z)  [rn, no fma]
//   pd  = fma(2, dot, -qxx) - xx_c    [== ((dot+dot)-qxx)-xx_c bitwise]
//   key = (~bits(min(pd,0)) & 0xFFFFF000) | (4095 - idx)
//
// R16 post-mortem: all load paths + both compute structures land at 63-65
// cyc/pt. Unified fit of R8/R9/R13/R15/R16: cost = 27.5 + 4.3*(chain ops)
// -- EVERY VALU op costs ~4.3 cyc => issue efficiency ~47%. Occupancy has
// been 50-67% for every 256-thr select, vs 80% for R12's 512-thr emit:
// consistent with a ~5-block/CU residency limit => 20 waves/CU. R17 tests
// it: select blocks = 1024 thr (4 query-groups x one slice, 4 KB LDS),
// grid (b,g2,s) = 1024 blocks -> 2 blocks/CU x 16 waves = 32 waves/CU.
// val_buf bit-identical to R15/R16 (same keys, same network); merge
// certificates ((a) strict 20-bit separation at rank 32/33, (b) slice
// exhaustion) and exact wave-per-query radix fallback unchanged.
// sigma_kernel widened 256->1024 thr (was single-block latency-serial).
// ===========================================================================

__device__ __forceinline__ int lane_rank(unsigned long long m) {
    return __builtin_amdgcn_mbcnt_hi((unsigned)(m >> 32),
           __builtin_amdgcn_mbcnt_lo((unsigned)m, 0u));
}

__device__ __forceinline__ unsigned umaxu(unsigned a, unsigned b) {
    return a > b ? a : b;   // v_max_u32
}
__device__ __forceinline__ unsigned uminu(unsigned a, unsigned b) {
    return a < b ? a : b;   // v_min_u32
}
// compare-exchange, descending: a gets max, b gets min (2 two-src ops)
#define CE(a, b) { unsigned _mx = umaxu(a, b); b = uminu(a, b); a = _mx; }

// --------------------------------------------------------------------------
// P: prep. pts4[b*4096+i] = (x,y,z,xx), V2 rn formula; resets flag_cnt.
// --------------------------------------------------------------------------
__global__ __launch_bounds__(256) void prep_kernel(
        const float* __restrict__ xyz, float4* __restrict__ pts4,
        int* __restrict__ flag_cnt) {
#pragma clang fp contract(off)
    const int p = blockIdx.x * 256 + threadIdx.x;
    if (p == 0) flag_cnt[0] = 0;
    const int b = p >> 12;
    const int i = p & (NN - 1);
    const float* xb = xyz + (size_t)b * (3 * NN);
    float x = xb[i], y = xb[NN + i], z = xb[2 * NN + i];
    float xx = ((x * x) + (y * y)) + (z * z);  // rn (contract off)
    pts4[p] = make_float4(x, y, z, xx);
}

// --------------------------------------------------------------------------
// A: select. grid 1024 = (b<<6)|(g2<<4)|s; 1024 thr = 1024 queries
// (4 query-groups) sharing slice s staged in 4 KB LDS. 32 waves/CU.
// Per-slice top-8 via the 8-point batched 2-src network (== R15/R16).
// --------------------------------------------------------------------------
__global__ __launch_bounds__(1024) void knn_select_kernel(
        const float4* __restrict__ pts4, unsigned* __restrict__ val_buf) {
#pragma clang fp contract(off)
    __shared__ float4 pts[SSZ];
    const int tid = threadIdx.x;
    const int blk = blockIdx.x;
    const int s = blk & 15;
    const int g2 = (blk >> 4) & 3;
    const int b = blk >> 6;
    const float4* pb = pts4 + (b << 12);

    if (tid < SSZ) pts[tid] = pb[(s << 8) | tid];
    const int q = (g2 << 10) | tid;
    const float4 qp = pb[q];
    const float qx = qp.x, qy = qp.y, qz = qp.z;
    const float nqxx = -qp.w;
    __syncthreads();

    unsigned h0=0,h1=0,h2=0,h3=0,h4=0,h5=0,h6=0,h7=0;
    const unsigned ibase = 4095u - (unsigned)(s << 8);  // idxterm = ibase - j

#define KY(ji, dst) { \
        float4 cp = pts[j0 + ji]; \
        float dot = __builtin_fmaf(qz, cp.z, \
                    __builtin_fmaf(qy, cp.y, qx * cp.x)); \
        float pd = __builtin_fmaf(2.0f, dot, nqxx) - cp.w; \
        pd = fminf(pd, 0.0f); \
        dst = (~__float_as_uint(pd) & 0xFFFFF000u) \
              | (ibase - (unsigned)(j0 + ji)); }

    for (int j0 = 0; j0 < SSZ; j0 += 8) {
        unsigned k0,k1,k2,k3,k4,k5,k6,k7;
        KY(0,k0) KY(1,k1) KY(2,k2) KY(3,k3)
        KY(4,k4) KY(5,k5) KY(6,k6) KY(7,k7)
        // sort 8 desc: Batcher odd-even mergesort (19 CE)
        CE(k0,k1) CE(k2,k3) CE(k0,k2) CE(k1,k3) CE(k1,k2)   // sort4 A
        CE(k4,k5) CE(k6,k7) CE(k4,k6) CE(k5,k7) CE(k5,k6)   // sort4 B
        CE(k0,k4) CE(k1,k5) CE(k2,k6) CE(k3,k7)             // OEM(4,4)
        CE(k2,k4) CE(k3,k5)
        CE(k1,k2) CE(k3,k4) CE(k5,k6)
        // half-cleaner: h_i = max(h_i, s_{7-i}) -> top-8 multiset, bitonic
        h0 = umaxu(h0, k7); h1 = umaxu(h1, k6);
        h2 = umaxu(h2, k5); h3 = umaxu(h3, k4);
        h4 = umaxu(h4, k3); h5 = umaxu(h5, k2);
        h6 = umaxu(h6, k1); h7 = umaxu(h7, k0);
        // bitonic merger: sort bitonic-8 desc (12 CE)
        CE(h0,h4) CE(h1,h5) CE(h2,h6) CE(h3,h7)
        CE(h0,h2) CE(h1,h3) CE(h4,h6) CE(h5,h7)
        CE(h0,h1) CE(h2,h3) CE(h4,h5) CE(h6,h7)
    }
#undef KY

    const int qg = (b << 12) | q;
    unsigned* vp = val_buf + (size_t)(s * CKEEP) * NQ + qg;  // desc t=0..7
#define ST(t, ht) vp[(size_t)(t) * NQ] = ht;
    ST(0,h0) ST(1,h1) ST(2,h2) ST(3,h3)
    ST(4,h4) ST(5,h5) ST(6,h6) ST(7,h7)
#undef ST
}

// --------------------------------------------------------------------------
// B: merge. 64-thr blocks; stage 16x8=128 keys/query to LDS (stride 129);
// 33-step 16-head merge. First 32 picks -> idx_out directly
// (idx = 4095 - (key & 4095)). Certificates -> flag list.
// --------------------------------------------------------------------------
__global__ __launch_bounds__(64) void knn_merge_kernel(
        const unsigned* __restrict__ val_buf, int* __restrict__ idx_out,
        int* __restrict__ flag_list, int* __restrict__ flag_cnt) {
    __shared__ unsigned lv[64 * 129];  // 33 KB
    const int tid = threadIdx.x;
    const int qg = blockIdx.x * 64 + tid;
    unsigned* my = lv + tid * 129;
    for (int t = 0; t < 128; ++t) my[t] = val_buf[(size_t)t * NQ + qg];

    int p0=0,p1=0,p2=0,p3=0,p4=0,p5=0,p6=0,p7=0,
        p8=0,p9=0,p10=0,p11=0,p12=0,p13=0,p14=0,p15=0;
    unsigned v0 =my[0],  v1 =my[8],  v2 =my[16],  v3 =my[24];
    unsigned v4 =my[32], v5 =my[40], v6 =my[48],  v7 =my[56];
    unsigned v8 =my[64], v9 =my[72], v10=my[80],  v11=my[88];
    unsigned v12=my[96], v13=my[104],v14=my[112], v15=my[120];
    int* outp = idx_out + (size_t)qg * KNN;
    unsigned key32 = 0u, key33 = 0u;
    for (int step = 0; step < 33; ++step) {
        unsigned best = v0; int bp = 0;
        if (v1  > best) { best = v1;  bp = 1; }
        if (v2  > best) { best = v2;  bp = 2; }
        if (v3  > best) { best = v3;  bp = 3; }
        if (v4  > best) { best = v4;  bp = 4; }
        if (v5  > best) { best = v5;  bp = 5; }
        if (v6  > best) { best = v6;  bp = 6; }
        if (v7  > best) { best = v7;  bp = 7; }
        if (v8  > best) { best = v8;  bp = 8; }
        if (v9  > best) { best = v9;  bp = 9; }
        if (v10 > best) { best = v10; bp = 10; }
        if (v11 > best) { best = v11; bp = 11; }
        if (v12 > best) { best = v12; bp = 12; }
        if (v13 > best) { best = v13; bp = 13; }
        if (v14 > best) { best = v14; bp = 14; }
        if (v15 > best) { best = v15; bp = 15; }
        if (step == 32) { key33 = best; break; }
        outp[step] = 4095 - (int)(best & 4095u);
        if (step == 31) key32 = best;
        if      (bp==0)  { ++p0;  v0  = (p0 <8)?my[p0]      :0u; }
        else if (bp==1)  { ++p1;  v1  = (p1 <8)?my[8+p1]    :0u; }
        else if (bp==2)  { ++p2;  v2  = (p2 <8)?my[16+p2]   :0u; }
        else if (bp==3)  { ++p3;  v3  = (p3 <8)?my[24+p3]   :0u; }
        else if (bp==4)  { ++p4;  v4  = (p4 <8)?my[32+p4]   :0u; }
        else if (bp==5)  { ++p5;  v5  = (p5 <8)?my[40+p5]   :0u; }
        else if (bp==6)  { ++p6;  v6  = (p6 <8)?my[48+p6]   :0u; }
        else if (bp==7)  { ++p7;  v7  = (p7 <8)?my[56+p7]   :0u; }
        else if (bp==8)  { ++p8;  v8  = (p8 <8)?my[64+p8]   :0u; }
        else if (bp==9)  { ++p9;  v9  = (p9 <8)?my[72+p9]   :0u; }
        else if (bp==10) { ++p10; v10 = (p10<8)?my[80+p10]  :0u; }
        else if (bp==11) { ++p11; v11 = (p11<8)?my[88+p11]  :0u; }
        else if (bp==12) { ++p12; v12 = (p12<8)?my[96+p12]  :0u; }
        else if (bp==13) { ++p13; v13 = (p13<8)?my[104+p13] :0u; }
        else if (bp==14) { ++p14; v14 = (p14<8)?my[112+p14] :0u; }
        else             { ++p15; v15 = (p15<8)?my[120+p15] :0u; }
    }

    // certificates: (a) strict 20-bit separation at the 32/33 boundary;
    // (b) every slice's 8th kept key < key33 (merge saw the true top-33).
    bool flag = ((key32 >> 12) == (key33 >> 12));
    for (int sl = 0; sl < 16; ++sl)
        flag = flag || (my[sl * 8 + 7] >= key33);
    if (flag) {
        int pos = atomicAdd(flag_cnt, 1);
        flag_list[pos] = qg;
    }
}

// --------------------------------------------------------------------------
// B2: exact fallback, wave-per-query over the compacted flag list.
// Full-precision mono keys in 64 statically-indexed VGPRs; 32-step radix
// select -> exact 32nd key; indices via ballot compaction (index order,
// eq-ties take first `budget` -- exact reference tie semantics).
// --------------------------------------------------------------------------
__global__ __launch_bounds__(256) void knn_fallback_kernel(
        const float* __restrict__ xyz, const int* __restrict__ flag_list,
        const int* __restrict__ flag_cnt, int* __restrict__ idx_out) {
#pragma clang fp contract(off)
    const int nflag = flag_cnt[0];
    const int lane = threadIdx.x & 63;
    const int wid = (blockIdx.x * 256 + threadIdx.x) >> 6;
    const int nw = (gridDim.x * 256) >> 6;
    for (int w = wid; w < nflag; w += nw) {
        const int qg = flag_list[w];
        const int b = qg >> 12;
        const int q = qg & (NN - 1);
        const float* xb = xyz + (size_t)b * (3 * NN);
        const float qx = xb[q], qy = xb[NN + q], qz = xb[2 * NN + q];
        const float qxx = ((qx * qx) + (qy * qy)) + (qz * qz);
        const float nqxx = -qxx;

        unsigned key[64];
#pragma unroll
        for (int i = 0; i < 64; ++i) {
            const int j = (i << 6) | lane;
            float x = xb[j], y = xb[NN + j], z = xb[2 * NN + j];
            float xxc = ((x * x) + (y * y)) + (z * z);
            float dot = __builtin_fmaf(qz, z, __builtin_fmaf(qy, y, qx * x));
            float pd = __builtin_fmaf(2.0f, dot, nqxx) - xxc;
            unsigned u = __float_as_uint(pd);
            key[i] = u ^ (unsigned)(((int)u >> 31) | 0x80000000);
        }

        // largest t with #{key >= t} >= 32  ==  32nd-largest key
        unsigned cur = 0u;
        for (int bit = 31; bit >= 0; --bit) {
            const unsigned cand = cur | (1u << bit);
            int c = 0;
#pragma unroll
            for (int i = 0; i < 64; ++i) c += (key[i] >= cand) ? 1 : 0;
#pragma unroll
            for (int o = 32; o >= 1; o >>= 1) c += __shfl_xor(c, o, 64);
            if (c >= 32) cur = cand;  // uniform after butterfly
        }

        // exact gt/eq totals
        int ge = 0;
#pragma unroll
        for (int i = 0; i < 64; ++i) {
            ge += (key[i] > cur) ? 1 : 0;
            ge += (key[i] == cur) ? 0x10000 : 0;
        }
#pragma unroll
        for (int o = 32; o >= 1; o >>= 1) ge += __shfl_xor(ge, o, 64);
        const int gt_total = ge & 0xFFFF;
        const int budget = min(ge >> 16, 32 - gt_total);

        int* outp = idx_out + (size_t)qg * KNN;
        int slot = 0, neq = 0;
#pragma unroll
        for (int i = 0; i < 64; ++i) {
            const bool isgt = key[i] > cur;
            const bool iseq = key[i] == cur;
            const unsigned long long mgt = __ballot(isgt);
            const unsigned long long meq = __ballot(iseq);
            if (isgt) outp[slot + lane_rank(mgt)] = (i << 6) | lane;
            if (iseq) {
                const int r = neq + lane_rank(meq);
                if (r < budget) outp[gt_total + r] = (i << 6) | lane;
            }
            slot += __builtin_popcountll(mgt);
            neq += __builtin_popcountll(meq);
        }
    }
}

// --------------------------------------------------------------------------
// gather / finalize: unchanged. sigma: widened to 1024 thr (R17).
// --------------------------------------------------------------------------
__global__ __launch_bounds__(256) void gather_minmax_kernel(
        const float* __restrict__ feats, const int* __restrict__ idx_in,
        float* __restrict__ mx_buf, float* __restrict__ mn_buf,
        double* __restrict__ partials) {
    const int tid = threadIdx.x;
    const int w = tid >> 6;
    const int lane = tid & 63;
    const int q = blockIdx.x * 4 + w;
    const int b = q >> 12;
    const float* fb = feats + (size_t)b * (NN * CC);
    const float center = feats[(size_t)q * CC + lane];
    const int* ip = idx_in + (size_t)q * KNN;

    float mx = -FLT_MAX, mn = FLT_MAX;
    double ss = 0.0;
#pragma unroll 4
    for (int k = 0; k < KNN; ++k) {
        int nb = ip[k];
        float v = fb[(size_t)nb * CC + lane];
        float off = v - center;
        mx = fmaxf(mx, off);
        mn = fminf(mn, off);
        double od = (double)off;
        ss = fma(od, od, ss);
    }
    mx_buf[(size_t)q * CC + lane] = mx;
    mn_buf[(size_t)q * CC + lane] = mn;

#pragma unroll
    for (int o = 32; o >= 1; o >>= 1) ss += __shfl_down(ss, o, 64);
    __shared__ double wsum[4];
    if (lane == 0) wsum[w] = ss;
    __syncthreads();
    if (tid == 0) partials[blockIdx.x] = (wsum[0] + wsum[1]) + (wsum[2] + wsum[3]);
}

__global__ __launch_bounds__(1024) void sigma_kernel(const double* __restrict__ partials,
                                                     float* __restrict__ sigma) {
    __shared__ double red[1024];
    double s = 0.0;
    for (int i = threadIdx.x; i < 16384; i += 1024) s += partials[i];
    red[threadIdx.x] = s;
    __syncthreads();
    for (int o = 512; o >= 1; o >>= 1) {
        if (threadIdx.x < o) red[threadIdx.x] += red[threadIdx.x + o];
        __syncthreads();
    }
    if (threadIdx.x == 0) sigma[0] = (float)(red[0] * (1.0 / 134217728.0));
}

__global__ __launch_bounds__(256) void finalize_kernel(
        const float* __restrict__ mx_buf, const float* __restrict__ mn_buf,
        const float* __restrict__ alpha, const float* __restrict__ beta,
        const float* __restrict__ sigma, float* __restrict__ out) {
#pragma clang fp contract(off)
    const int e = blockIdx.x * 256 + threadIdx.x;
    const int c = e & (CC - 1);
    const float s = sigma[0] + 1e-5f;
    const float a = alpha[c];
    const float bt = beta[c];
    const float off = (a >= 0.f) ? mx_buf[e] : mn_buf[e];
    const float t = off / s;
    out[e] = (t * a) + bt;
}

extern "C" void kernel_launch(void* const* d_in, const int* in_sizes, int n_in,
                              void* d_out, int out_size, void* d_ws, size_t ws_size,
                              hipStream_t stream) {
    (void)in_sizes; (void)n_in; (void)out_size; (void)ws_size;
    const float* xyz   = (const float*)d_in[0];  // [16,3,4096]
    const float* feats = (const float*)d_in[1];  // [16,4096,64]
    const float* alpha = (const float*)d_in[2];  // [64]
    const float* beta  = (const float*)d_in[3];  // [64]
    float* out = (float*)d_out;                  // [16,4096,64]

    char* ws = (char*)d_ws;
    // Lifetimes:
    //   val_buf   [0, 33,554,432)          select->merge(read); dead after.
    //   mx/mn     alias val region          written by gather (post-merge).
    //   idx_buf   [33,554,432, 41,943,040)  merge/fallback write, gather reads.
    //   flag_list [41,943,040, +256 KB)     merge->fallback.
    //   flag_cnt  42,205,184 (4 B)
    //   pts4      [42,205,248, +1 MB)       prep->select; dead after select.
    //   partials  alias pts4 start          written by gather.
    //   sigma     43,254,784 (after pts4)
    unsigned* val_buf  = (unsigned*)ws;
    float*    mx_buf   = (float*)ws;                  // [0, 16.78M)
    float*    mn_buf   = (float*)(ws + 16777216);     // [16.78M, 33.55M)
    int*      idx_buf  = (int*)(ws + 33554432);
    int*      flag_list= (int*)(ws + 41943040);
    int*      flag_cnt = (int*)(ws + 42205184);
    float4*   pts4     = (float4*)(ws + 42205248);    // 64B-aligned
    double*   partials = (double*)(ws + 42205248);    // alias pts4 (dead)
    float*    sigma    = (float*)(ws + 43254784);

    prep_kernel<<<NQ / 256, 256, 0, stream>>>(xyz, pts4, flag_cnt);
    knn_select_kernel<<<BB * 4 * NSLICE, 1024, 0, stream>>>(pts4, val_buf);
    knn_merge_kernel<<<NQ / 64, 64, 0, stream>>>(val_buf, idx_buf,
                                                 flag_list, flag_cnt);
    knn_fallback_kernel<<<256, 256, 0, stream>>>(xyz, flag_list, flag_cnt,
                                                 idx_buf);
    gather_minmax_kernel<<<NQ / 4, 256, 0, stream>>>(feats, idx_buf, mx_buf,
                                                     mn_buf, partials);
    sigma_kernel<<<1, 1024, 0, stream>>>(partials, sigma);
    finalize_kernel<<<(NQ * CC) / 256, 256, 0, stream>>>(mx_buf, mn_buf, alpha,
                                                         beta, sigma, out);
}